// Round 14
// baseline (372.345 us; speedup 1.0000x reference)
//
#include <hip/hip_runtime.h>

#define N_NODES 50000
#define F_IN 128
#define OUT_F 128
#define JF 256
#define EDGES 600000
#define BN_EPS 1e-5f
#define MAXDEG 48
#define NPART 8
#define PART_ROWS 6250
#define BKCAP 163840        // bucket capacity per partition
#define LCAP 256            // LDS bin capacity
#define EB_PER_SIDE 586     // ceil(600000/1024)
#define EDGE_B (2*EB_PER_SIDE)
#define CONVX_B 6250
#define CONVW_B 32
#define BUILDA_B (EDGE_B + CONVX_B + CONVW_B)
#define SCATB_B 2048
#define CHUNK_REC 512       // records per ticket chunk
#define ROWS_PB 16
#define GATH_B 3125         // N/16 exactly
#define GEMM_ROWS 32
#define GEMM_B 1563         // 1563*32 = 50016
#define HPAD 50048
#define NCOPY 16

typedef __attribute__((ext_vector_type(8))) short short8;
typedef __attribute__((ext_vector_type(4))) float floatx4;
typedef __attribute__((ext_vector_type(4))) unsigned short ushortx4;
typedef __attribute__((ext_vector_type(4))) unsigned int uintx4;

static __device__ __forceinline__ unsigned short f2bf(float f) {
    unsigned int x = __float_as_uint(f);
    unsigned int r = (x + 0x7fffu + ((x >> 16) & 1u)) >> 16;
    return (unsigned short)r;
}
static __device__ __forceinline__ float bflo(unsigned int p) { return __uint_as_float(p << 16); }
static __device__ __forceinline__ float bfhi(unsigned int p) { return __uint_as_float(p & 0xffff0000u); }

// physical XCD id (HW-verified readable on gfx950; m09)
static __device__ __forceinline__ unsigned xcc_id() {
    unsigned x;
    asm volatile("s_getreg_b32 %0, hwreg(HW_REG_XCC_ID, 0, 32)" : "=s"(x));
    return x & (NPART - 1);
}

// ---------------------------------------------------------------------------
// build_a: single-pass edge binning into per-partition buckets via LDS bins,
// plus x->bf16 and W->bf16 (k'-order). Record: {r|side<<20, (c<<16)|bf16(v)}.
// ---------------------------------------------------------------------------
__global__ __launch_bounds__(256) void build_a(
    const int* __restrict__ rows0, const int* __restrict__ cols0, const float* __restrict__ vals0,
    const int* __restrict__ rows1, const int* __restrict__ cols1, const float* __restrict__ vals1,
    uint2* __restrict__ buckets, int* __restrict__ gcur,
    const floatx4* __restrict__ x4, ushortx4* __restrict__ xb4,
    const float* __restrict__ W, uint2* __restrict__ Wb2)
{
    int bid = blockIdx.x;
    int tid = threadIdx.x;
    if (bid < EDGE_B) {
        __shared__ int   lcnt_[NPART];
        __shared__ int   lbase[NPART];
        __shared__ uint2 lbuf[NPART][LCAP];   // 16 KB

        if (tid < NPART) lcnt_[tid] = 0;
        __syncthreads();

        int side = bid >= EB_PER_SIDE;
        int b = side ? bid - EB_PER_SIDE : bid;
        const int*   rows = side ? rows1 : rows0;
        const int*   cols = side ? cols1 : cols0;
        const float* vals = side ? vals1 : vals0;

        int e = b * 1024 + tid * 4;
        if (e < EDGES) {
            int4 rv = *(const int4*)(rows + e);
            int4 cv = *(const int4*)(cols + e);
            float4 vv = *(const float4*)(vals + e);
            int rr[4] = {rv.x, rv.y, rv.z, rv.w};
            int cc[4] = {cv.x, cv.y, cv.z, cv.w};
            float ff[4] = {vv.x, vv.y, vv.z, vv.w};
            #pragma unroll
            for (int j = 0; j < 4; ++j) {
                unsigned part = (unsigned)rr[j] / (unsigned)PART_ROWS;
                uint2 q;
                q.x = (unsigned)rr[j] | ((unsigned)side << 20);
                q.y = ((unsigned)cc[j] << 16) | f2bf(ff[j]);
                int pos = atomicAdd(&lcnt_[part], 1);
                if (pos < LCAP) {
                    lbuf[part][pos] = q;
                } else {
                    int gp = atomicAdd(&gcur[part], 1);
                    if (gp < BKCAP) buckets[(size_t)part * BKCAP + gp] = q;
                }
            }
        }
        __syncthreads();
        if (tid < NPART) {
            int c = lcnt_[tid]; if (c > LCAP) c = LCAP;
            lcnt_[tid] = c;
            lbase[tid] = atomicAdd(&gcur[tid], c);
        }
        __syncthreads();
        #pragma unroll
        for (int p = 0; p < NPART; ++p) {
            int c = lcnt_[p], base = lbase[p];
            for (int j = tid; j < c; j += 256) {
                int gp = base + j;
                if (gp < BKCAP) buckets[(size_t)p * BKCAP + gp] = lbuf[p][j];
            }
        }
    } else if (bid < EDGE_B + CONVX_B) {
        int i = (bid - EDGE_B) * 256 + tid;
        floatx4 v = __builtin_nontemporal_load(&x4[i]);
        ushortx4 o;
        o.x = f2bf(v.x); o.y = f2bf(v.y); o.z = f2bf(v.z); o.w = f2bf(v.w);
        __builtin_nontemporal_store(o, &xb4[i]);
    } else {
        int i = (bid - EDGE_B - CONVX_B) * 256 + tid;   // 0..8191
        int col = i >> 6, l = i & 63;
        const float* wr = W + (size_t)col * JF;
        float a0 = wr[2 * l], a1 = wr[2 * l + 1];
        float b0 = wr[128 + 2 * l], b1 = wr[128 + 2 * l + 1];
        uint2 o;
        o.x = (unsigned int)f2bf(a0) | ((unsigned int)f2bf(a1) << 16);
        o.y = (unsigned int)f2bf(b0) | ((unsigned int)f2bf(b1) << 16);
        Wb2[col * 64 + l] = o;
    }
}

// ---------------------------------------------------------------------------
// build_b: XCC-pinned ELL scatter. Each block reads its PHYSICAL XCD id and
// claims 512-record chunks of that XCD's partition via a ticket; falls
// through to other partitions when exhausted (correctness is mapping-
// independent; affinity is the fast path). ELL region (2.4 MB/partition)
// stays in the owning XCD's L2 -> writes merge before writeback.
// ---------------------------------------------------------------------------
__global__ __launch_bounds__(256) void build_b(
    const uint2* __restrict__ buckets, const int* __restrict__ gcur,
    int* __restrict__ ticket,
    int* __restrict__ cnt0, int* __restrict__ cnt1,
    unsigned int* __restrict__ pe0, unsigned int* __restrict__ pe1)
{
    __shared__ int t_sh;
    unsigned myp = xcc_id();
    int tid = threadIdx.x;

    for (int pp = 0; pp < NPART; ++pp) {
        unsigned part = (myp + pp) & (NPART - 1);
        int n = gcur[part]; if (n > BKCAP) n = BKCAP;
        int nch = (n + CHUNK_REC - 1) / CHUNK_REC;
        const uint2* bk = buckets + (size_t)part * BKCAP;

        for (;;) {
            __syncthreads();
            if (tid == 0) t_sh = atomicAdd(&ticket[part], 1);
            __syncthreads();
            int t = t_sh;
            if (t >= nch) break;

            int base = t * CHUNK_REC + tid * 2;
            if (base < n) {
                uintx4 q2 = __builtin_nontemporal_load((const uintx4*)(bk + base));
                {
                    unsigned r = q2.x & 0xFFFFFu;
                    unsigned side = q2.x >> 20;
                    int* cnt = side ? cnt1 : cnt0;
                    unsigned int* pe = side ? pe1 : pe0;
                    int p = atomicAdd(&cnt[r], 1);
                    if (p < MAXDEG) pe[(size_t)r * MAXDEG + p] = q2.y;
                }
                if (base + 1 < n) {
                    unsigned r = q2.z & 0xFFFFFu;
                    unsigned side = q2.z >> 20;
                    int* cnt = side ? cnt1 : cnt0;
                    unsigned int* pe = side ? pe1 : pe0;
                    int p = atomicAdd(&cnt[r], 1);
                    if (p < MAXDEG) pe[(size_t)r * MAXDEG + p] = q2.w;
                }
            }
        }
    }
}

// ---------------------------------------------------------------------------
// ELL record accumulate; _m masks boundary slots, _u unconditional.
// ---------------------------------------------------------------------------
static __device__ __forceinline__ void rec_u(
    unsigned int q, int lane,
    const unsigned int* __restrict__ xb32, float& A0, float& A1)
{
    unsigned int xv = xb32[(q >> 16) * 64 + lane];
    float vv = __uint_as_float(q << 16);
    A0 += vv * bflo(xv);
    A1 += vv * bfhi(xv);
}
static __device__ __forceinline__ void rec_m(
    unsigned int q, bool on, int lane,
    const unsigned int* __restrict__ xb32, float& A0, float& A1)
{
    unsigned int idx = on ? (q >> 16) : 0u;
    float vv = on ? __uint_as_float(q << 16) : 0.0f;
    unsigned int xv = xb32[idx * 64 + lane];
    A0 += vv * bflo(xv);
    A1 += vv * bfhi(xv);
}

// ---------------------------------------------------------------------------
// High-occupancy gather: 16 rows/block, 3.3 KB LDS, 8 blocks/CU. Writes
// h-tilde bf16 rows, k'-interleaved: lane l -> {h[2l],h[2l+1],h[128+2l],h[128+2l+1]}.
// ---------------------------------------------------------------------------
__global__ __launch_bounds__(256, 8) void gather_kernel(
    const unsigned int* __restrict__ xb32,
    const int* __restrict__ cnt0, const unsigned int* __restrict__ pe0,
    const int* __restrict__ cnt1, const unsigned int* __restrict__ pe1,
    uint2* __restrict__ hb)
{
    __shared__ uint4 recs[2][ROWS_PB][6];
    __shared__ int   lcnt[2][ROWS_PB];

    int tid = threadIdx.x;
    int lane = tid & 63;
    int w = tid >> 6;
    int wu = __builtin_amdgcn_readfirstlane(w);
    int row0 = blockIdx.x * ROWS_PB;

    if (tid < 192) {
        int lr = tid / 12;
        int rem = tid - lr * 12;
        int side = rem >= 6;
        int g = rem - side * 6;
        const unsigned int* pe = side ? pe1 : pe0;
        recs[side][lr][g] = *(const uint4*)(pe + (size_t)(row0 + lr) * MAXDEG + g * 4);
    }
    if (tid < 2 * ROWS_PB) {
        int side = tid >= ROWS_PB;
        int lr = tid & (ROWS_PB - 1);
        int d = (side ? cnt1 : cnt0)[row0 + lr];
        if (d > MAXDEG) d = MAXDEG;
        lcnt[side][lr] = d;
    }
    __syncthreads();

    for (int rr = 0; rr < 4; ++rr) {
        int lr = wu * 4 + rr;
        int r = row0 + lr;
        int d0 = __builtin_amdgcn_readfirstlane(lcnt[0][lr]);
        int d1 = __builtin_amdgcn_readfirstlane(lcnt[1][lr]);

        float aL0 = 0.f, aL1 = 0.f, aR0 = 0.f, aR1 = 0.f;

        #pragma unroll
        for (int g = 0; g < 6; ++g) {
            if (g * 4 < d0) {
                uint4 q = recs[0][lr][g];
                rec_u(q.x, lane, xb32, aL0, aL1);
                rec_m(q.y, g * 4 + 1 < d0, lane, xb32, aL0, aL1);
                rec_m(q.z, g * 4 + 2 < d0, lane, xb32, aL0, aL1);
                rec_m(q.w, g * 4 + 3 < d0, lane, xb32, aL0, aL1);
            }
        }
        #pragma unroll
        for (int g = 0; g < 6; ++g) {
            if (g * 4 < d1) {
                uint4 q = recs[1][lr][g];
                rec_u(q.x, lane, xb32, aR0, aR1);
                rec_m(q.y, g * 4 + 1 < d1, lane, xb32, aR0, aR1);
                rec_m(q.z, g * 4 + 2 < d1, lane, xb32, aR0, aR1);
                rec_m(q.w, g * 4 + 3 < d1, lane, xb32, aR0, aR1);
            }
        }
        if (d0 > 24)
            for (int p = 24; p < d0; ++p)
                rec_u(pe0[(size_t)r * MAXDEG + p], lane, xb32, aL0, aL1);
        if (d1 > 24)
            for (int p = 24; p < d1; ++p)
                rec_u(pe1[(size_t)r * MAXDEG + p], lane, xb32, aR0, aR1);

        uint2 o;
        o.x = (unsigned int)f2bf(aL0) | ((unsigned int)f2bf(aL1) << 16);
        o.y = (unsigned int)f2bf(aR0) | ((unsigned int)f2bf(aR1) << 16);
        hb[(size_t)r * 64 + lane] = o;
    }
}

// ---------------------------------------------------------------------------
// MFMA GEMM, no LDS: wave w does 16 rows x 64 cols; A-frags loaded DIRECTLY
// from hb (k'-interleaved layout -> coalesced 16B frags). Bias + y + stats.
// ---------------------------------------------------------------------------
__global__ __launch_bounds__(256, 6) void gemm_kernel(
    const char* __restrict__ hb,
    const ushort* __restrict__ Wb,
    const float* __restrict__ bias,
    float* __restrict__ y, float* __restrict__ stats)
{
    __shared__ float lstat[256];

    int tid = threadIdx.x;
    int lane = tid & 63;
    int w = tid >> 6;
    int row0 = blockIdx.x * GEMM_ROWS + (w & 1) * 16;
    int cbase = (w >> 1) * 64;

    lstat[tid] = 0.f;
    __syncthreads();

    int colb = lane & 15;
    int kg = lane >> 4;
    const char* abase = hb + (size_t)(row0 + colb) * 512 + kg * 16;

    floatx4 acc[4];
    #pragma unroll
    for (int c = 0; c < 4; ++c) acc[c] = (floatx4){0.f, 0.f, 0.f, 0.f};

    #pragma unroll
    for (int k0 = 0; k0 < 8; ++k0) {
        short8 a = *(const short8*)(abase + k0 * 64);
        #pragma unroll
        for (int c = 0; c < 4; ++c) {
            short8 b = *(const short8*)(Wb + (size_t)(cbase + c * 16 + colb) * 256 + k0 * 32 + kg * 8);
            acc[c] = __builtin_amdgcn_mfma_f32_16x16x32_bf16(a, b, acc[c], 0, 0, 0);
        }
    }

    #pragma unroll
    for (int c = 0; c < 4; ++c) {
        int col = cbase + c * 16 + colb;
        float bv = bias[col];
        float s = 0.f, s2 = 0.f;
        #pragma unroll
        for (int q = 0; q < 4; ++q) {
            int row = row0 + kg * 4 + q;
            if (row < N_NODES) {
                float val = acc[c][q] + bv;
                y[(size_t)row * OUT_F + col] = val;
                s += val; s2 += val * val;
            }
        }
        atomicAdd(&lstat[col], s);
        atomicAdd(&lstat[128 + col], s2);
    }
    __syncthreads();
    float* sdst = stats + (size_t)(blockIdx.x & (NCOPY - 1)) * 256;
    atomicAdd(&sdst[tid], lstat[tid]);
}

// ---------------------------------------------------------------------------
// BN scale/shift prep: fold NCOPY stat replicas.
// ---------------------------------------------------------------------------
__global__ void bn_prep(const float* __restrict__ stats,
                        const float* __restrict__ gamma,
                        const float* __restrict__ beta,
                        float* __restrict__ ss)
{
    int o = threadIdx.x;
    if (o >= OUT_F) return;
    float s = 0.f, s2 = 0.f;
    #pragma unroll
    for (int c = 0; c < NCOPY; ++c) {
        s  += stats[c * 256 + o];
        s2 += stats[c * 256 + 128 + o];
    }
    float inv_n = 1.0f / (float)N_NODES;
    float mean = s * inv_n;
    float var  = s2 * inv_n - mean * mean;
    float sc = rsqrtf(var + BN_EPS) * gamma[o];
    ss[o] = sc;
    ss[OUT_F + o] = beta[o] - mean * sc;
}

// ---------------------------------------------------------------------------
// BN apply.
// ---------------------------------------------------------------------------
__global__ __launch_bounds__(256) void bn_apply(
    float* __restrict__ y, const float* __restrict__ ss)
{
    size_t i = (size_t)blockIdx.x * blockDim.x + threadIdx.x;
    size_t total = (size_t)N_NODES * OUT_F / 4;
    if (i >= total) return;

    int c4 = (int)(i & (OUT_F / 4 - 1));
    float4 v  = ((const float4*)y)[i];
    float4 sc = ((const float4*)ss)[c4];
    float4 sh = ((const float4*)(ss + OUT_F))[c4];
    v.x = v.x * sc.x + sh.x;
    v.y = v.y * sc.y + sh.y;
    v.z = v.z * sc.z + sh.z;
    v.w = v.w * sc.w + sh.w;
    ((float4*)y)[i] = v;
}

extern "C" void kernel_launch(void* const* d_in, const int* in_sizes, int n_in,
                              void* d_out, int out_size, void* d_ws, size_t ws_size,
                              hipStream_t stream)
{
    const float* x     = (const float*)d_in[0];
    const int*   rows0 = (const int*)  d_in[1];
    const int*   cols0 = (const int*)  d_in[2];
    const float* vals0 = (const float*)d_in[3];
    const int*   rows1 = (const int*)  d_in[4];
    const int*   cols1 = (const int*)  d_in[5];
    const float* vals1 = (const float*)d_in[6];
    const float* W     = (const float*)d_in[7];
    const float* b     = (const float*)d_in[8];
    const float* gamma = (const float*)d_in[9];
    const float* beta  = (const float*)d_in[10];

    float* y = (float*)d_out;

    // workspace layout (buckets UNION hb: consumed by build_b before gather)
    ushort* xb = (ushort*)d_ws;                                  // 12.8 MB
    ushort* Wb = xb + (size_t)N_NODES * F_IN;                    // 64 KB (k' order)
    unsigned int* pe0 = (unsigned int*)(Wb + OUT_F * JF);        // 9.6 MB
    unsigned int* pe1 = pe0 + (size_t)N_NODES * MAXDEG;          // 9.6 MB
    uint2* hb = (uint2*)(pe1 + (size_t)N_NODES * MAXDEG);        // 25.6 MB
    uint2* buckets = hb;                                         // union (10.5 MB)
    int* gcur = (int*)(hb + (size_t)HPAD * 64);                  // 8  <- zero region
    int* ticket = gcur + NPART;                                  // 8
    int* cnt0 = ticket + NPART;                                  // N
    int* cnt1 = cnt0 + N_NODES;                                  // N
    float* stats = (float*)(cnt1 + N_NODES);                     // NCOPY*256
    float* ss    = stats + NCOPY * 256;                          // 256

    hipMemsetAsync(gcur, 0,
                   ((size_t)2 * NPART + 2 * N_NODES + NCOPY * 256) * sizeof(int),
                   stream);

    build_a<<<BUILDA_B, 256, 0, stream>>>(
        rows0, cols0, vals0, rows1, cols1, vals1,
        buckets, gcur,
        (const floatx4*)x, (ushortx4*)xb, W, (uint2*)Wb);

    build_b<<<SCATB_B, 256, 0, stream>>>(buckets, gcur, ticket,
                                         cnt0, cnt1, pe0, pe1);

    gather_kernel<<<GATH_B, 256, 0, stream>>>(
        (const unsigned int*)xb, cnt0, pe0, cnt1, pe1, hb);

    gemm_kernel<<<GEMM_B, 256, 0, stream>>>(
        (const char*)hb, Wb, b, y, stats);

    bn_prep<<<1, 128, 0, stream>>>(stats, gamma, beta, ss);
    bn_apply<<<CONVX_B, 256, 0, stream>>>(y, ss);
}

// Round 15
// 170.243 us; speedup vs baseline: 2.1871x; 2.1871x over previous
//
#include <hip/hip_runtime.h>

#define N_NODES 50000
#define F_IN 128
#define OUT_F 128
#define JF 256
#define EDGES 600000
#define BN_EPS 1e-5f
#define MAXDEG 48
#define NPART 8
#define PART_ROWS 6250   // N_NODES / NPART
#define CHUNK_E 2048
#define NCHUNK 586       // 586*2048 >= 2E

#define SCAT_B (NPART * NCHUNK)   // 4688
#define CONVX_B 6250     // N*F_IN/4/256
#define CONVW_B 32       // 128*64/256
#define BUILD_B (SCAT_B + CONVX_B + CONVW_B)
#define ROWS_PB 32
#define GATH_B 1563      // ceil(N/32)
#define GEMM_ROWS 32
#define GEMM_B 1563
#define HPAD 50048
#define NCOPY 16

typedef __attribute__((ext_vector_type(8))) short short8;
typedef __attribute__((ext_vector_type(4))) float floatx4;
typedef __attribute__((ext_vector_type(4))) unsigned short ushortx4;

static __device__ __forceinline__ unsigned short f2bf(float f) {
    unsigned int x = __float_as_uint(f);
    unsigned int r = (x + 0x7fffu + ((x >> 16) & 1u)) >> 16;
    return (unsigned short)r;
}
static __device__ __forceinline__ float bflo(unsigned int p) { return __uint_as_float(p << 16); }
static __device__ __forceinline__ float bfhi(unsigned int p) { return __uint_as_float(p & 0xffff0000u); }

// ---------------------------------------------------------------------------
// Fused build (round-10 verbatim): XCD-partitioned row-major ELL scatter +
// x -> bf16 + W -> bf16 in k'-interleaved order (k' 4l+{0..3} <->
// {2l, 2l+1, 128+2l, 128+2l+1}).
// ---------------------------------------------------------------------------
__global__ __launch_bounds__(256) void build_kernel(
    const int* __restrict__ rows0, const int* __restrict__ cols0, const float* __restrict__ vals0,
    const int* __restrict__ rows1, const int* __restrict__ cols1, const float* __restrict__ vals1,
    int* __restrict__ cnt0, int* __restrict__ cnt1,
    unsigned int* __restrict__ pe0, unsigned int* __restrict__ pe1,
    const floatx4* __restrict__ x4, ushortx4* __restrict__ xb4,
    const float* __restrict__ W, uint2* __restrict__ Wb2)
{
    int bid = blockIdx.x;
    int tid = threadIdx.x;
    if (bid < SCAT_B) {
        unsigned part = (unsigned)(bid & (NPART - 1));
        int c0 = (bid >> 3) * CHUNK_E;

        bool pure0 = (c0 + CHUNK_E <= EDGES);
        bool pure1 = (c0 >= EDGES) && (c0 + CHUNK_E <= 2 * EDGES);
        if (pure0 || pure1) {
            const int*   rows = pure1 ? rows1 : rows0;
            const int*   cols = pure1 ? cols1 : cols0;
            const float* vals = pure1 ? vals1 : vals0;
            int*          cnt = pure1 ? cnt1 : cnt0;
            unsigned int*  pe = pure1 ? pe1 : pe0;
            int eb = pure1 ? c0 - EDGES : c0;
            #pragma unroll
            for (int g = 0; g < 2; ++g) {
                int e = eb + g * 1024 + tid * 4;
                int4 rv = *(const int4*)(rows + e);
                int rr[4] = {rv.x, rv.y, rv.z, rv.w};
                #pragma unroll
                for (int j = 0; j < 4; ++j) {
                    int r = rr[j];
                    if ((unsigned)r / (unsigned)PART_ROWS == part) {
                        int ee = e + j;
                        int c = cols[ee];
                        float v = vals[ee];
                        int p = atomicAdd(&cnt[r], 1);
                        if (p < MAXDEG)
                            pe[(size_t)r * MAXDEG + p] = ((unsigned int)c << 16) | f2bf(v);
                    }
                }
            }
        } else {
            for (int i = 0; i < CHUNK_E / 256; ++i) {
                int e = c0 + i * 256 + tid;
                if (e < 2 * EDGES) {
                    bool s1 = e >= EDGES;
                    int ee = s1 ? e - EDGES : e;
                    int r = s1 ? rows1[ee] : rows0[ee];
                    if ((unsigned)r / (unsigned)PART_ROWS == part) {
                        int c = s1 ? cols1[ee] : cols0[ee];
                        float v = s1 ? vals1[ee] : vals0[ee];
                        int* cnt = s1 ? cnt1 : cnt0;
                        unsigned int* pe = s1 ? pe1 : pe0;
                        int p = atomicAdd(&cnt[r], 1);
                        if (p < MAXDEG)
                            pe[(size_t)r * MAXDEG + p] = ((unsigned int)c << 16) | f2bf(v);
                    }
                }
            }
        }
    } else if (bid < SCAT_B + CONVX_B) {
        int i = (bid - SCAT_B) * 256 + tid;
        floatx4 v = __builtin_nontemporal_load(&x4[i]);
        ushortx4 o;
        o.x = f2bf(v.x); o.y = f2bf(v.y); o.z = f2bf(v.z); o.w = f2bf(v.w);
        __builtin_nontemporal_store(o, &xb4[i]);
    } else {
        // W -> Wb in k'-interleaved order
        int i = (bid - SCAT_B - CONVX_B) * 256 + tid;   // 0..8191
        int col = i >> 6, l = i & 63;
        const float* wr = W + (size_t)col * JF;
        float a0 = wr[2 * l], a1 = wr[2 * l + 1];
        float b0 = wr[128 + 2 * l], b1 = wr[128 + 2 * l + 1];
        uint2 o;
        o.x = (unsigned int)f2bf(a0) | ((unsigned int)f2bf(a1) << 16);
        o.y = (unsigned int)f2bf(b0) | ((unsigned int)f2bf(b1) << 16);
        Wb2[col * 64 + l] = o;
    }
}

// ---------------------------------------------------------------------------
// ELL record accumulate; _m masks boundary slots, _u unconditional.
// ---------------------------------------------------------------------------
static __device__ __forceinline__ void rec_u(
    unsigned int q, int lane,
    const unsigned int* __restrict__ xb32, float& A0, float& A1)
{
    unsigned int xv = xb32[(q >> 16) * 64 + lane];
    float vv = __uint_as_float(q << 16);
    A0 += vv * bflo(xv);
    A1 += vv * bfhi(xv);
}
static __device__ __forceinline__ void rec_m(
    unsigned int q, bool on, int lane,
    const unsigned int* __restrict__ xb32, float& A0, float& A1)
{
    unsigned int idx = on ? (q >> 16) : 0u;
    float vv = on ? __uint_as_float(q << 16) : 0.0f;
    unsigned int xv = xb32[idx * 64 + lane];
    A0 += vv * bflo(xv);
    A1 += vv * bfhi(xv);
}

// ---------------------------------------------------------------------------
// High-occupancy gather (round-10 verbatim): 32 rows/block, 6.3 KB LDS,
// wave-uniform group skips. Writes h-tilde bf16 rows in k'-interleaved
// order: lane l -> {h[2l],h[2l+1],h[128+2l],h[128+2l+1]} at hb[row*64+l].
// ---------------------------------------------------------------------------
__global__ __launch_bounds__(256, 8) void gather_kernel(
    const unsigned int* __restrict__ xb32,
    const int* __restrict__ cnt0, const unsigned int* __restrict__ pe0,
    const int* __restrict__ cnt1, const unsigned int* __restrict__ pe1,
    uint2* __restrict__ hb)
{
    __shared__ uint4 recs[2][ROWS_PB][6];        // 6 KB
    __shared__ int   lcnt[2][ROWS_PB];

    int tid = threadIdx.x;
    int lane = tid & 63;
    int w = tid >> 6;
    int wu = __builtin_amdgcn_readfirstlane(w);
    int row0 = blockIdx.x * ROWS_PB;

    // stage records + counts into LDS (coalesced)
    {
        int idx = tid;
        #pragma unroll
        for (int pass = 0; pass < 2; ++pass) {
            if (idx < 384) {
                int lr = idx / 12;
                int rem = idx - lr * 12;
                int side = rem >= 6;
                int g = rem - side * 6;
                int r = row0 + lr; if (r >= N_NODES) r = N_NODES - 1;
                const unsigned int* pe = side ? pe1 : pe0;
                recs[side][lr][g] = *(const uint4*)(pe + (size_t)r * MAXDEG + g * 4);
            }
            idx += 256;
        }
        if (tid < 64) {
            int side = tid >= ROWS_PB;
            int lr = tid & (ROWS_PB - 1);
            int r = row0 + lr;
            int d = 0;
            if (r < N_NODES) d = (side ? cnt1 : cnt0)[r];
            if (d > MAXDEG) d = MAXDEG;
            lcnt[side][lr] = d;
        }
    }
    __syncthreads();

    // gather 8 rows per wave
    for (int rr = 0; rr < 8; ++rr) {
        int lr = wu * 8 + rr;
        int r = row0 + lr;
        int d0 = __builtin_amdgcn_readfirstlane(lcnt[0][lr]);
        int d1 = __builtin_amdgcn_readfirstlane(lcnt[1][lr]);

        float aL0 = 0.f, aL1 = 0.f, aR0 = 0.f, aR1 = 0.f;

        #pragma unroll
        for (int g = 0; g < 6; ++g) {
            if (g * 4 < d0) {
                uint4 q = recs[0][lr][g];
                rec_u(q.x, lane, xb32, aL0, aL1);
                rec_m(q.y, g * 4 + 1 < d0, lane, xb32, aL0, aL1);
                rec_m(q.z, g * 4 + 2 < d0, lane, xb32, aL0, aL1);
                rec_m(q.w, g * 4 + 3 < d0, lane, xb32, aL0, aL1);
            }
        }
        #pragma unroll
        for (int g = 0; g < 6; ++g) {
            if (g * 4 < d1) {
                uint4 q = recs[1][lr][g];
                rec_u(q.x, lane, xb32, aR0, aR1);
                rec_m(q.y, g * 4 + 1 < d1, lane, xb32, aR0, aR1);
                rec_m(q.z, g * 4 + 2 < d1, lane, xb32, aR0, aR1);
                rec_m(q.w, g * 4 + 3 < d1, lane, xb32, aR0, aR1);
            }
        }
        // rare tails (deg > 24)
        if (d0 > 24 && r < N_NODES)
            for (int p = 24; p < d0; ++p)
                rec_u(pe0[(size_t)r * MAXDEG + p], lane, xb32, aL0, aL1);
        if (d1 > 24 && r < N_NODES)
            for (int p = 24; p < d1; ++p)
                rec_u(pe1[(size_t)r * MAXDEG + p], lane, xb32, aR0, aR1);

        uint2 o;
        o.x = (unsigned int)f2bf(aL0) | ((unsigned int)f2bf(aL1) << 16);
        o.y = (unsigned int)f2bf(aR0) | ((unsigned int)f2bf(aR1) << 16);
        hb[(size_t)(row0 + lr) * 64 + lane] = o;
    }
}

// ---------------------------------------------------------------------------
// MFMA GEMM (round-13 verbatim), no LDS: wave w does 16 rows x 64 cols;
// A-frags loaded DIRECTLY from hb (k'-interleave makes lane(colb,kg)'s 16B
// frag contiguous, coalesced across the wave). Bias + y + BN stats.
// ---------------------------------------------------------------------------
__global__ __launch_bounds__(256, 6) void gemm_kernel(
    const char* __restrict__ hb,
    const ushort* __restrict__ Wb,
    const float* __restrict__ bias,
    float* __restrict__ y, float* __restrict__ stats)
{
    __shared__ float lstat[256];

    int tid = threadIdx.x;
    int lane = tid & 63;
    int w = tid >> 6;
    int row0 = blockIdx.x * GEMM_ROWS + (w & 1) * 16;
    int cbase = (w >> 1) * 64;

    lstat[tid] = 0.f;
    __syncthreads();

    int colb = lane & 15;
    int kg = lane >> 4;
    const char* abase = hb + (size_t)(row0 + colb) * 512 + kg * 16;

    floatx4 acc[4];
    #pragma unroll
    for (int c = 0; c < 4; ++c) acc[c] = (floatx4){0.f, 0.f, 0.f, 0.f};

    #pragma unroll
    for (int k0 = 0; k0 < 8; ++k0) {
        short8 a = *(const short8*)(abase + k0 * 64);
        #pragma unroll
        for (int c = 0; c < 4; ++c) {
            short8 b = *(const short8*)(Wb + (size_t)(cbase + c * 16 + colb) * 256 + k0 * 32 + kg * 8);
            acc[c] = __builtin_amdgcn_mfma_f32_16x16x32_bf16(a, b, acc[c], 0, 0, 0);
        }
    }

    #pragma unroll
    for (int c = 0; c < 4; ++c) {
        int col = cbase + c * 16 + colb;
        float bv = bias[col];
        float s = 0.f, s2 = 0.f;
        #pragma unroll
        for (int q = 0; q < 4; ++q) {
            int row = row0 + kg * 4 + q;
            if (row < N_NODES) {
                float val = acc[c][q] + bv;
                y[(size_t)row * OUT_F + col] = val;
                s += val; s2 += val * val;
            }
        }
        atomicAdd(&lstat[col], s);
        atomicAdd(&lstat[128 + col], s2);
    }
    __syncthreads();
    float* sdst = stats + (size_t)(blockIdx.x & (NCOPY - 1)) * 256;
    atomicAdd(&sdst[tid], lstat[tid]);
}

// ---------------------------------------------------------------------------
// BN scale/shift prep: fold NCOPY stat replicas.
// ---------------------------------------------------------------------------
__global__ void bn_prep(const float* __restrict__ stats,
                        const float* __restrict__ gamma,
                        const float* __restrict__ beta,
                        float* __restrict__ ss)
{
    int o = threadIdx.x;
    if (o >= OUT_F) return;
    float s = 0.f, s2 = 0.f;
    #pragma unroll
    for (int c = 0; c < NCOPY; ++c) {
        s  += stats[c * 256 + o];
        s2 += stats[c * 256 + 128 + o];
    }
    float inv_n = 1.0f / (float)N_NODES;
    float mean = s * inv_n;
    float var  = s2 * inv_n - mean * mean;
    float sc = rsqrtf(var + BN_EPS) * gamma[o];
    ss[o] = sc;
    ss[OUT_F + o] = beta[o] - mean * sc;
}

// ---------------------------------------------------------------------------
// BN apply.
// ---------------------------------------------------------------------------
__global__ __launch_bounds__(256) void bn_apply(
    float* __restrict__ y, const float* __restrict__ ss)
{
    size_t i = (size_t)blockIdx.x * blockDim.x + threadIdx.x;
    size_t total = (size_t)N_NODES * OUT_F / 4;
    if (i >= total) return;

    int c4 = (int)(i & (OUT_F / 4 - 1));
    float4 v  = ((const float4*)y)[i];
    float4 sc = ((const float4*)ss)[c4];
    float4 sh = ((const float4*)(ss + OUT_F))[c4];
    v.x = v.x * sc.x + sh.x;
    v.y = v.y * sc.y + sh.y;
    v.z = v.z * sc.z + sh.z;
    v.w = v.w * sc.w + sh.w;
    ((float4*)y)[i] = v;
}

extern "C" void kernel_launch(void* const* d_in, const int* in_sizes, int n_in,
                              void* d_out, int out_size, void* d_ws, size_t ws_size,
                              hipStream_t stream)
{
    const float* x     = (const float*)d_in[0];
    const int*   rows0 = (const int*)  d_in[1];
    const int*   cols0 = (const int*)  d_in[2];
    const float* vals0 = (const float*)d_in[3];
    const int*   rows1 = (const int*)  d_in[4];
    const int*   cols1 = (const int*)  d_in[5];
    const float* vals1 = (const float*)d_in[6];
    const float* W     = (const float*)d_in[7];
    const float* b     = (const float*)d_in[8];
    const float* gamma = (const float*)d_in[9];
    const float* beta  = (const float*)d_in[10];

    float* y = (float*)d_out;

    // workspace layout
    ushort* xb = (ushort*)d_ws;                                  // 12.8 MB
    ushort* Wb = xb + (size_t)N_NODES * F_IN;                    // 64 KB (k' order)
    unsigned int* pe0 = (unsigned int*)(Wb + OUT_F * JF);        // 9.6 MB
    unsigned int* pe1 = pe0 + (size_t)N_NODES * MAXDEG;          // 9.6 MB
    uint2* hb = (uint2*)(pe1 + (size_t)N_NODES * MAXDEG);        // 25.6 MB
    int* cnt0 = (int*)(hb + (size_t)HPAD * 64);                  // N  <- zero region
    int* cnt1 = cnt0 + N_NODES;                                  // N
    float* stats = (float*)(cnt1 + N_NODES);                     // NCOPY*256
    float* ss    = stats + NCOPY * 256;                          // 256

    hipMemsetAsync(cnt0, 0,
                   (2 * (size_t)N_NODES + NCOPY * 256) * sizeof(int),
                   stream);

    build_kernel<<<BUILD_B, 256, 0, stream>>>(
        rows0, cols0, vals0, rows1, cols1, vals1,
        cnt0, cnt1, pe0, pe1,
        (const floatx4*)x, (ushortx4*)xb, W, (uint2*)Wb);

    gather_kernel<<<GATH_B, 256, 0, stream>>>(
        (const unsigned int*)xb, cnt0, pe0, cnt1, pe1, hb);

    gemm_kernel<<<GEMM_B, 256, 0, stream>>>(
        (const char*)hb, Wb, b, y, stats);

    bn_prep<<<1, 128, 0, stream>>>(stats, gamma, beta, ss);
    bn_apply<<<CONVX_B, 256, 0, stream>>>(y, ss);
}